// Round 8
// baseline (219.258 us; speedup 1.0000x reference)
//
#include <hip/hip_runtime.h>

typedef __attribute__((ext_vector_type(8))) short s16x8;
typedef __attribute__((ext_vector_type(4))) float f32x4;
typedef __attribute__((ext_vector_type(4))) unsigned short u16x4;

#define T_  2048
#define C_  1024
#define D_  64

__device__ __forceinline__ unsigned short f2bf(float f){
  union { float fv; unsigned int u; } v; v.fv = f;
  unsigned int r = v.u + 0x7FFFu + ((v.u >> 16) & 1u);
  return (unsigned short)(r >> 16);
}

__device__ __forceinline__ float exp2_asm(float x){
  float r; asm("v_exp_f32 %0, %1" : "=v"(r) : "v"(x)); return r;
}
__device__ __forceinline__ unsigned int cvtpk(float lo, float hi){
  unsigned int r; asm("v_cvt_pk_bf16_f32 %0, %1, %2" : "=v"(r) : "v"(lo), "v"(hi)); return r;
}

__device__ __forceinline__ void gload_lds16(const void* g, void* l){
  __builtin_amdgcn_global_load_lds(
      (const __attribute__((address_space(1))) unsigned int*)g,
      (__attribute__((address_space(3))) unsigned int*)l, 16, 0, 0);
}

// ---------------- fp32 -> bf16 convert, 8 elems/thread ----------------
__global__ __launch_bounds__(256) void cvt_kernel(const float* __restrict__ src,
                                                  unsigned short* __restrict__ dst){
  size_t i = ((size_t)blockIdx.x * 256u + threadIdx.x) * 8u;
  f32x4 a = *(const f32x4*)(src + i);
  f32x4 b = *(const f32x4*)(src + i + 4);
  s16x8 o;
  #pragma unroll
  for (int j = 0; j < 4; ++j){ o[j] = (short)f2bf(a[j]); o[4+j] = (short)f2bf(b[j]); }
  *(s16x8*)(dst + i) = o;
}

// ---------------- GEMM 128x256xK, ring-4 LDS pipeline, BK=32 ----------------
// C[m,n] = sum_k A[m,k]*Bw[n,k] + bias[n].  512 thr = 8 waves (2M x 4N),
// wave-tile 64x64.  4-slot LDS ring: during tile t we stage tile t+3 into
// slot (t+3)&3 (never the slot being read; old occupant freed by this tile's
// head barrier).  Head of t: counted s_waitcnt vmcnt(6) (tile t's 3 loads had
// 3 tiles of time to land; queue never drains until the last tile) + ONE raw
// s_barrier per K-step.  Chunk-XOR swizzle (c ^= (row>>1)&3, 64B rows) with
// inverse-swizzled global source keeps ds_read conflicts at zero.
template<int MODE>
__global__ __launch_bounds__(512, 2) void gemm_bt(
    const unsigned short* __restrict__ A, const unsigned short* __restrict__ Bw,
    const float* __restrict__ bias, int M, int N, int K, int nbx,
    unsigned short* __restrict__ q_ws, unsigned short* __restrict__ k_ws,
    unsigned short* __restrict__ vT_ws, float* __restrict__ out)
{
  __shared__ unsigned short Asl[4][128*32];   //  8 KB x4
  __shared__ unsigned short Bsl[4][256*32];   // 16 KB x4   (96 KB total)
  const int tid = threadIdx.x;
  const int lane = tid & 63, wid = tid >> 6;
  const int g = lane >> 4, lr = lane & 15;
  const int wm = wid >> 2, wn = wid & 3;
  const int nwg = (int)gridDim.x;
  const int cpx = nwg >> 3;
  const int orig = (int)blockIdx.x;
  const int wgid = (orig & 7) * cpx + (orig >> 3);   // XCD-chunked (nwg % 8 == 0)
  const int bx = wgid % nbx, by = wgid / nbx;
  const int m0 = by * 128, n0 = bx * 256;

  f32x4 acc[4][4];
  #pragma unroll
  for (int i = 0; i < 4; ++i)
    #pragma unroll
    for (int j = 0; j < 4; ++j) acc[i][j] = (f32x4){0.f,0.f,0.f,0.f};

  auto stageA = [&](int kt, int slot){
    const int k0 = kt << 5;
    const int n = tid;                       // 512 chunks = 128 rows x 4
    const int row = n >> 2, cd = n & 3;
    const int cs = cd ^ ((row >> 1) & 3);
    gload_lds16((const char*)A + ((size_t)(m0+row)*K + k0)*2 + cs*16,
                (char*)&Asl[slot][0] + n*16);
  };
  auto stageB = [&](int kt, int slot){
    const int k0 = kt << 5;
    #pragma unroll
    for (int j = 0; j < 2; ++j){
      const int n = j*512 + tid;             // 1024 chunks = 256 rows x 4
      const int row = n >> 2, cd = n & 3;
      const int cs = cd ^ ((row >> 1) & 3);
      gload_lds16((const char*)Bw + ((size_t)(n0+row)*K + k0)*2 + cs*16,
                  (char*)&Bsl[slot][0] + n*16);
    }
  };
  auto rdA = [&](int slot, int mi){
    const int row = wm*64 + mi*16 + lr;
    return *(const s16x8*)((const char*)&Asl[slot][0] + row*64 + (((g ^ (row>>1)) & 3) << 4));
  };
  auto rdB = [&](int slot, int ni){
    const int row = wn*64 + ni*16 + lr;
    return *(const s16x8*)((const char*)&Bsl[slot][0] + row*64 + (((g ^ (row>>1)) & 3) << 4));
  };

  const int nk = K >> 5;                     // 32
  stageA(0, 0); stageB(0, 0);
  stageA(1, 1); stageB(1, 1);
  stageA(2, 2); stageB(2, 2);                // 9 loads outstanding

  for (int t = 0; t < nk; ++t){
    const int slot = t & 3;
    if (t < nk - 2)       asm volatile("s_waitcnt vmcnt(6)" ::: "memory");  // tile t landed
    else if (t == nk - 2) asm volatile("s_waitcnt vmcnt(3)" ::: "memory");
    else                  asm volatile("s_waitcnt vmcnt(0)" ::: "memory");
    asm volatile("s_barrier" ::: "memory");  // slot (t+3)&3's old occupant now free

    // ---- phase 0: B frags + A frags 0-1, stage A(t+3), 8 MFMA
    s16x8 bf[4];
    #pragma unroll
    for (int ni = 0; ni < 4; ++ni) bf[ni] = rdB(slot, ni);
    s16x8 a0 = rdA(slot, 0), a1 = rdA(slot, 1);
    if (t + 3 < nk) stageA(t + 3, (t + 3) & 3);
    __builtin_amdgcn_s_setprio(1);
    #pragma unroll
    for (int ni = 0; ni < 4; ++ni){
      acc[0][ni] = __builtin_amdgcn_mfma_f32_16x16x32_bf16(a0, bf[ni], acc[0][ni], 0, 0, 0);
      acc[1][ni] = __builtin_amdgcn_mfma_f32_16x16x32_bf16(a1, bf[ni], acc[1][ni], 0, 0, 0);
    }
    __builtin_amdgcn_s_setprio(0);

    // ---- phase 1: A frags 2-3, stage B(t+3), 8 MFMA
    s16x8 a2 = rdA(slot, 2), a3 = rdA(slot, 3);
    if (t + 3 < nk) stageB(t + 3, (t + 3) & 3);
    __builtin_amdgcn_s_setprio(1);
    #pragma unroll
    for (int ni = 0; ni < 4; ++ni){
      acc[2][ni] = __builtin_amdgcn_mfma_f32_16x16x32_bf16(a2, bf[ni], acc[2][ni], 0, 0, 0);
      acc[3][ni] = __builtin_amdgcn_mfma_f32_16x16x32_bf16(a3, bf[ni], acc[3][ni], 0, 0, 0);
    }
    __builtin_amdgcn_s_setprio(0);
  }

  #pragma unroll
  for (int mi = 0; mi < 4; ++mi){
    #pragma unroll
    for (int ni = 0; ni < 4; ++ni){
      const int n = n0 + wn*64 + ni*16 + lr;
      const float bv = bias[n];
      #pragma unroll
      for (int r = 0; r < 4; ++r){
        const int m = m0 + wm*64 + mi*16 + g*4 + r;
        const float val = acc[mi][ni][r] + bv;
        if (MODE == 0){
          const int which = n >> 10;
          const int cc = n & 1023;
          const int h = cc >> 6, d = cc & 63;
          const int bq = m >> 11, t = m & 2047;
          const int bh = bq*16 + h;
          // q pre-scaled by log2(e)/64 so attention works in exp2 domain
          if (which == 0)      q_ws[((size_t)bh*T_ + t)*D_ + d] = f2bf(val * 0.022542110013890054f);
          else if (which == 1) k_ws[((size_t)bh*T_ + t)*D_ + d] = f2bf(val);
          else                 vT_ws[((size_t)bh*D_ + d)*T_ + t] = f2bf(val);
        } else {
          out[(size_t)m*N + n] = val;
        }
      }
    }
  }
}

// ---------------- flash attention v5: balanced pairs, shared K/V staging ----------------
__global__ __launch_bounds__(256, 4) void attn_kernel(
    const unsigned short* __restrict__ q_ws, const unsigned short* __restrict__ k_ws,
    const unsigned short* __restrict__ vT_ws, unsigned short* __restrict__ y_ws)
{
  __shared__ __align__(16) unsigned short Ks[2][64*64];   // [key][d]  8KB x2 (P aliases Ks[cur])
  __shared__ __align__(16) unsigned short Vs[2][64*64];   // [d][key]  8KB x2

  const int tid = threadIdx.x;
  const int lane = tid & 63, wid = tid >> 6;
  const int g = lane >> 4, lr = lane & 15;
  const int orig = (int)blockIdx.x;
  const int wgid = (orig & 7) * 128 + (orig >> 3);        // XCD-chunk
  const int p  = wgid & 15;
  const int bh = wgid >> 4;
  const int qwA = p*64 + wid*16,  qwB = (31 - p)*64 + wid*16;
  const int qrowA = qwA + lr,     qrowB = qwB + lr;
  const int swz = (lr & 7) << 4;

  const unsigned short* Qb = q_ws  + (size_t)bh*T_*D_;
  const unsigned short* Kb = k_ws  + (size_t)bh*T_*D_;
  const unsigned short* Vb = vT_ws + (size_t)bh*D_*T_;

  auto stage = [&](int t, int buf){
    const int kt0 = t << 6;
    #pragma unroll
    for (int s = 0; s < 2; ++s){
      const int c = s*256 + tid;
      const int r = c >> 3;
      const int scol = ((c & 7) << 4) ^ ((r & 7) << 4);
      gload_lds16((const char*)Kb + ((size_t)(kt0 + r)*D_)*2 + scol,
                  (char*)&Ks[buf][0] + c*16);
      gload_lds16((const char*)Vb + ((size_t)r*T_ + kt0)*2 + scol,
                  (char*)&Vs[buf][0] + c*16);
    }
  };

  const s16x8 bqA0 = *(const s16x8*)&Qb[(size_t)(qwA+lr)*D_ + g*8];
  const s16x8 bqA1 = *(const s16x8*)&Qb[(size_t)(qwA+lr)*D_ + 32 + g*8];
  const s16x8 bqB0 = *(const s16x8*)&Qb[(size_t)(qwB+lr)*D_ + g*8];
  const s16x8 bqB1 = *(const s16x8*)&Qb[(size_t)(qwB+lr)*D_ + 32 + g*8];

  s16x8 ones;
  #pragma unroll
  for (int j = 0; j < 8; ++j) ones[j] = (short)0x3F80;

  f32x4 yA[4], yB[4];
  #pragma unroll
  for (int dt = 0; dt < 4; ++dt){ yA[dt] = (f32x4){0.f,0.f,0.f,0.f}; yB[dt] = (f32x4){0.f,0.f,0.f,0.f}; }
  f32x4 lacA = (f32x4){0.f,0.f,0.f,0.f}, lacB = (f32x4){0.f,0.f,0.f,0.f};
  float mA = -1e30f, mB = -1e30f;

  const int ntA = p + 1, ntB = 32 - p;
  stage(0, 0);
  __syncthreads();

  for (int t = 0; t < ntB; ++t){
    const int cur = t & 1;
    if (t + 1 < ntB) stage(t + 1, cur ^ 1);
    const int kt0 = t << 6;
    const unsigned short* Kt = &Ks[cur][0];
    const unsigned short* Vt = &Vs[cur][0];
    unsigned short* Pw = &Ks[cur][wid*1024];
    const bool actA = (t < ntA);                 // wave-uniform

    f32x4 sB[4], sA[4];
    #pragma unroll
    for (int kk = 0; kk < 4; ++kk){
      const int row = kk*16 + lr;
      const s16x8 a0 = *(const s16x8*)&Kt[row*64 + (((g*16)      ^ swz) >> 1)];
      const s16x8 a1 = *(const s16x8*)&Kt[row*64 + (((64 + g*16) ^ swz) >> 1)];
      f32x4 acc = (f32x4){0.f,0.f,0.f,0.f};
      acc = __builtin_amdgcn_mfma_f32_16x16x32_bf16(a0, bqB0, acc, 0, 0, 0);
      acc = __builtin_amdgcn_mfma_f32_16x16x32_bf16(a1, bqB1, acc, 0, 0, 0);
      sB[kk] = acc;
      if (actA){
        f32x4 acc2 = (f32x4){0.f,0.f,0.f,0.f};
        acc2 = __builtin_amdgcn_mfma_f32_16x16x32_bf16(a0, bqA0, acc2, 0, 0, 0);
        acc2 = __builtin_amdgcn_mfma_f32_16x16x32_bf16(a1, bqA1, acc2, 0, 0, 0);
        sA[kk] = acc2;
      }
    }

    if (kt0 + 63 > qwB){
      #pragma unroll
      for (int kk = 0; kk < 4; ++kk)
        #pragma unroll
        for (int r = 0; r < 4; ++r)
          if (kt0 + kk*16 + g*4 + r > qrowB) sB[kk][r] = -1e30f;
    }
    {
      float m01 = fmaxf(fmaxf(sB[0][0], sB[0][1]), fmaxf(sB[0][2], sB[0][3]));
      float m23 = fmaxf(fmaxf(sB[1][0], sB[1][1]), fmaxf(sB[1][2], sB[1][3]));
      float m45 = fmaxf(fmaxf(sB[2][0], sB[2][1]), fmaxf(sB[2][2], sB[2][3]));
      float m67 = fmaxf(fmaxf(sB[3][0], sB[3][1]), fmaxf(sB[3][2], sB[3][3]));
      float mx = fmaxf(fmaxf(m01, m23), fmaxf(m45, m67));
      mx = fmaxf(mx, __shfl_xor(mx, 16, 64));
      mx = fmaxf(mx, __shfl_xor(mx, 32, 64));
      if (!__all(mx <= mB + 8.f)){
        const float mnew = fmaxf(mB, mx);
        const float corr = exp2_asm(mB - mnew);
        mB = mnew;
        lacB[0] *= corr;
        #pragma unroll
        for (int dt = 0; dt < 4; ++dt)
          #pragma unroll
          for (int r = 0; r < 4; ++r) yB[dt][r] *= corr;
      }
    }
    union { unsigned int u[2]; u16x4 v; } pkB[4];
    #pragma unroll
    for (int kk = 0; kk < 4; ++kk){
      const float e0 = exp2_asm(sB[kk][0] - mB);
      const float e1 = exp2_asm(sB[kk][1] - mB);
      const float e2 = exp2_asm(sB[kk][2] - mB);
      const float e3 = exp2_asm(sB[kk][3] - mB);
      pkB[kk].u[0] = cvtpk(e0, e1);
      pkB[kk].u[1] = cvtpk(e2, e3);
    }

    asm volatile("s_barrier" ::: "memory");

    #pragma unroll
    for (int kk = 0; kk < 4; ++kk)
      *(u16x4*)&Pw[lr*64 + (((kk*32 + g*8) ^ swz) >> 1)] = pkB[kk].v;
    asm volatile("" ::: "memory");
    {
      const s16x8 p0 = *(const s16x8*)&Pw[lr*64 + (((g*16)      ^ swz) >> 1)];
      const s16x8 p1 = *(const s16x8*)&Pw[lr*64 + (((64 + g*16) ^ swz) >> 1)];
      lacB = __builtin_amdgcn_mfma_f32_16x16x32_bf16(ones, p0, lacB, 0, 0, 0);
      lacB = __builtin_amdgcn_mfma_f32_16x16x32_bf16(ones, p1, lacB, 0, 0, 0);
      #pragma unroll
      for (int dt = 0; dt < 4; ++dt){
        const int vrow = dt*16 + lr;
        const s16x8 v0 = *(const s16x8*)&Vt[vrow*64 + (((g*16)      ^ swz) >> 1)];
        const s16x8 v1 = *(const s16x8*)&Vt[vrow*64 + (((64 + g*16) ^ swz) >> 1)];
        yB[dt] = __builtin_amdgcn_mfma_f32_16x16x32_bf16(v0, p0, yB[dt], 0, 0, 0);
        yB[dt] = __builtin_amdgcn_mfma_f32_16x16x32_bf16(v1, p1, yB[dt], 0, 0, 0);
      }
    }

    if (actA){
      if (kt0 + 63 > qwA){
        #pragma unroll
        for (int kk = 0; kk < 4; ++kk)
          #pragma unroll
          for (int r = 0; r < 4; ++r)
            if (kt0 + kk*16 + g*4 + r > qrowA) sA[kk][r] = -1e30f;
      }
      float m01 = fmaxf(fmaxf(sA[0][0], sA[0][1]), fmaxf(sA[0][2], sA[0][3]));
      float m23 = fmaxf(fmaxf(sA[1][0], sA[1][1]), fmaxf(sA[1][2], sA[1][3]));
      float m45 = fmaxf(fmaxf(sA[2][0], sA[2][1]), fmaxf(sA[2][2], sA[2][3]));
      float m67 = fmaxf(fmaxf(sA[3][0], sA[3][1]), fmaxf(sA[3][2], sA[3][3]));
      float mx = fmaxf(fmaxf(m01, m23), fmaxf(m45, m67));
      mx = fmaxf(mx, __shfl_xor(mx, 16, 64));
      mx = fmaxf(mx, __shfl_xor(mx, 32, 64));
      if (!__all(mx <= mA + 8.f)){
        const float mnew = fmaxf(mA, mx);
        const float corr = exp2_asm(mA - mnew);
        mA = mnew;
        lacA[0] *= corr;
        #pragma unroll
        for (int dt = 0; dt < 4; ++dt)
          #pragma unroll
          for (int r = 0; r < 4; ++r) yA[dt][r] *= corr;
      }
      union { unsigned int u[2]; u16x4 v; } pkA[4];
      #pragma unroll
      for (int kk = 0; kk < 4; ++kk){
        const float e0 = exp2_asm(sA[kk][0] - mA);
        const float e1 = exp2_asm(sA[kk][1] - mA);
        const float e2 = exp2_asm(sA[kk][2] - mA);
        const float e3 = exp2_asm(sA[kk][3] - mA);
        pkA[kk].u[0] = cvtpk(e0, e1);
        pkA[kk].u[1] = cvtpk(e2, e3);
      }
      asm volatile("" ::: "memory");
      #pragma unroll
      for (int kk = 0; kk < 4; ++kk)
        *(u16x4*)&Pw[lr*64 + (((kk*32 + g*8) ^ swz) >> 1)] = pkA[kk].v;
      asm volatile("" ::: "memory");
      const s16x8 p0 = *(const s16x8*)&Pw[lr*64 + (((g*16)      ^ swz) >> 1)];
      const s16x8 p1 = *(const s16x8*)&Pw[lr*64 + (((64 + g*16) ^ swz) >> 1)];
      lacA = __builtin_amdgcn_mfma_f32_16x16x32_bf16(ones, p0, lacA, 0, 0, 0);
      lacA = __builtin_amdgcn_mfma_f32_16x16x32_bf16(ones, p1, lacA, 0, 0, 0);
      #pragma unroll
      for (int dt = 0; dt < 4; ++dt){
        const int vrow = dt*16 + lr;
        const s16x8 v0 = *(const s16x8*)&Vt[vrow*64 + (((g*16)      ^ swz) >> 1)];
        const s16x8 v1 = *(const s16x8*)&Vt[vrow*64 + (((64 + g*16) ^ swz) >> 1)];
        yA[dt] = __builtin_amdgcn_mfma_f32_16x16x32_bf16(v0, p0, yA[dt], 0, 0, 0);
        yA[dt] = __builtin_amdgcn_mfma_f32_16x16x32_bf16(v1, p1, yA[dt], 0, 0, 0);
      }
    }

    __syncthreads();
  }

  const int bq = bh >> 4, h = bh & 15;
  {
    const float inv = 1.f / lacB[0];
    #pragma unroll
    for (int dt = 0; dt < 4; ++dt){
      union { unsigned int u[2]; u16x4 v; } w;
      w.u[0] = cvtpk(yB[dt][0]*inv, yB[dt][1]*inv);
      w.u[1] = cvtpk(yB[dt][2]*inv, yB[dt][3]*inv);
      *(u16x4*)&y_ws[((size_t)(bq*T_ + qwB + lr))*C_ + h*64 + dt*16 + g*4] = w.v;
    }
  }
  {
    const float inv = 1.f / lacA[0];
    #pragma unroll
    for (int dt = 0; dt < 4; ++dt){
      union { unsigned int u[2]; u16x4 v; } w;
      w.u[0] = cvtpk(yA[dt][0]*inv, yA[dt][1]*inv);
      w.u[1] = cvtpk(yA[dt][2]*inv, yA[dt][3]*inv);
      *(u16x4*)&y_ws[((size_t)(bq*T_ + qwA + lr))*C_ + h*64 + dt*16 + g*4] = w.v;
    }
  }
}

extern "C" void kernel_launch(void* const* d_in, const int* in_sizes, int n_in,
                              void* d_out, int out_size, void* d_ws, size_t ws_size,
                              hipStream_t stream) {
  const float* x  = (const float*)d_in[0];
  const float* Wa = (const float*)d_in[1];
  const float* ba = (const float*)d_in[2];
  const float* Wp = (const float*)d_in[3];
  const float* bp = (const float*)d_in[4];
  float* out = (float*)d_out;

  char* ws = (char*)d_ws;
  const size_t MB = 1024u*1024u;
  unsigned short* xb  = (unsigned short*)(ws + 0);       // 16 MiB  [8192][1024] bf16
  unsigned short* wab = (unsigned short*)(ws + 16*MB);   //  6 MiB  [3072][1024]
  unsigned short* wpb = (unsigned short*)(ws + 22*MB);   //  2 MiB  [1024][1024]
  unsigned short* qws = (unsigned short*)(ws + 24*MB);   // 16 MiB  [64][2048][64]
  unsigned short* kws = (unsigned short*)(ws + 40*MB);   // 16 MiB  [64][2048][64]
  unsigned short* vT  = (unsigned short*)(ws + 56*MB);   // 16 MiB  [64][64][2048]
  unsigned short* yws = (unsigned short*)(ws + 72*MB);   // 16 MiB  [8192][1024]

  cvt_kernel<<<4096, 256, 0, stream>>>(x,  xb);
  cvt_kernel<<<1536, 256, 0, stream>>>(Wa, wab);
  cvt_kernel<<< 512, 256, 0, stream>>>(Wp, wpb);

  // QKV: M=8192 (64 tiles of 128), N=3072 (12 tiles of 256) -> 768 blocks = 3 CU-rounds
  gemm_bt<0><<<dim3(768), 512, 0, stream>>>(xb, wab, ba, 8192, 3072, 1024, 12,
                                            qws, kws, vT, nullptr);
  attn_kernel<<<dim3(1024), 256, 0, stream>>>(qws, kws, vT, yws);
  // proj: M=8192, N=1024 (4 tiles of 256) -> 256 blocks = 1 CU-round
  gemm_bt<1><<<dim3(256), 512, 0, stream>>>(yws, wpb, bp, 8192, 1024, 1024, 4,
                                            nullptr, nullptr, nullptr, out);
}

// Round 9
// 195.017 us; speedup vs baseline: 1.1243x; 1.1243x over previous
//
#include <hip/hip_runtime.h>

typedef __attribute__((ext_vector_type(8))) short s16x8;
typedef __attribute__((ext_vector_type(4))) float f32x4;
typedef __attribute__((ext_vector_type(4))) unsigned short u16x4;

#define T_  2048
#define C_  1024
#define D_  64

__device__ __forceinline__ unsigned short f2bf(float f){
  union { float fv; unsigned int u; } v; v.fv = f;
  unsigned int r = v.u + 0x7FFFu + ((v.u >> 16) & 1u);
  return (unsigned short)(r >> 16);
}

__device__ __forceinline__ float exp2_asm(float x){
  float r; asm("v_exp_f32 %0, %1" : "=v"(r) : "v"(x)); return r;
}
__device__ __forceinline__ unsigned int cvtpk(float lo, float hi){
  unsigned int r; asm("v_cvt_pk_bf16_f32 %0, %1, %2" : "=v"(r) : "v"(lo), "v"(hi)); return r;
}

__device__ __forceinline__ void gload_lds16(const void* g, void* l){
  __builtin_amdgcn_global_load_lds(
      (const __attribute__((address_space(1))) unsigned int*)g,
      (__attribute__((address_space(3))) unsigned int*)l, 16, 0, 0);
}

// ---------------- fp32 -> bf16 convert, 8 elems/thread ----------------
__global__ __launch_bounds__(256) void cvt_kernel(const float* __restrict__ src,
                                                  unsigned short* __restrict__ dst){
  size_t i = ((size_t)blockIdx.x * 256u + threadIdx.x) * 8u;
  f32x4 a = *(const f32x4*)(src + i);
  f32x4 b = *(const f32x4*)(src + i + 4);
  s16x8 o;
  #pragma unroll
  for (int j = 0; j < 4; ++j){ o[j] = (short)f2bf(a[j]); o[4+j] = (short)f2bf(b[j]); }
  *(s16x8*)(dst + i) = o;
}

// ---------------- GEMM 128x128xK, BK=64, dbuf + counted vmcnt ----------------
// C[m,n] = sum_k A[m,k]*Bw[n,k] + bias[n].  256 thr = 4 waves (2x2), wave-tile
// 64x64.  LDS 64 KB total -> 2 blocks/CU co-resident (stall cover).  Schedule:
// head { vmcnt(8): tile t landed, t+1 in flight; s_barrier }, 2x16 MFMA
// phases, tail { s_barrier; stage(t+2, buf t&1) } -- queue never drains to 0
// until the last tile; tile t+1 gets one full iteration to land.
// Reads conflict-free: 128B rows XOR-swizzled (byte ^= (row&7)<<4), inverse
// swizzle on the global source (rule #21).
template<int MODE>
__global__ __launch_bounds__(256, 2) void gemm_bt(
    const unsigned short* __restrict__ A, const unsigned short* __restrict__ Bw,
    const float* __restrict__ bias, int M, int N, int K, int nbx,
    unsigned short* __restrict__ q_ws, unsigned short* __restrict__ k_ws,
    unsigned short* __restrict__ vT_ws, float* __restrict__ out)
{
  __shared__ unsigned short Asm[2][128*64];   // 16 KB x2
  __shared__ unsigned short Bsm[2][128*64];   // 16 KB x2  (64 KB total)
  const int tid = threadIdx.x;
  const int lane = tid & 63, wid = tid >> 6;
  const int g = lane >> 4, lr = lane & 15;
  const int wr = wid >> 1, wc = wid & 1;
  const int nwg = (int)gridDim.x;
  const int cpx = nwg >> 3;
  const int orig = (int)blockIdx.x;
  const int wgid = (orig & 7) * cpx + (orig >> 3);   // XCD-chunked (nwg % 8 == 0)
  const int bx = wgid % nbx, by = wgid / nbx;
  const int m0 = by * 128, n0 = bx * 128;
  const int swz = (lr & 7) << 4;

  f32x4 acc[4][4];
  #pragma unroll
  for (int i = 0; i < 4; ++i)
    #pragma unroll
    for (int j = 0; j < 4; ++j) acc[i][j] = (f32x4){0.f,0.f,0.f,0.f};

  auto stage = [&](int kt, int buf){
    const int k0 = kt << 6;
    #pragma unroll
    for (int j = 0; j < 4; ++j){
      const int c = j*256 + tid;             // 1024 chunks = 128 rows x 8
      const int row = c >> 3, jc = c & 7;
      const int sc = (jc ^ (row & 7)) << 4;  // inverse swizzle on source
      gload_lds16((const char*)A  + ((size_t)(m0+row)*K + k0)*2 + sc,
                  (char*)&Asm[buf][0] + (size_t)c*16);
      gload_lds16((const char*)Bw + ((size_t)(n0+row)*K + k0)*2 + sc,
                  (char*)&Bsm[buf][0] + (size_t)c*16);
    }
  };

  const int nk = K >> 6;
  stage(0, 0);
  stage(1, 1);                               // 16 outstanding

  for (int t = 0; t < nk; ++t){
    const int cur = t & 1;
    if (t < nk - 1) asm volatile("s_waitcnt vmcnt(8)" ::: "memory");  // tile t landed
    else            asm volatile("s_waitcnt vmcnt(0)" ::: "memory");
    asm volatile("s_barrier" ::: "memory");

    const char* At = (const char*)&Asm[cur][0];
    const char* Bt = (const char*)&Bsm[cur][0];

    #pragma unroll
    for (int s = 0; s < 2; ++s){             // two K-halves: 16 MFMA each
      s16x8 af[4], bf[4];
      #pragma unroll
      for (int mi = 0; mi < 4; ++mi){
        const int row = wr*64 + mi*16 + lr;
        af[mi] = *(const s16x8*)(At + row*128 + ((s*64 + g*16) ^ swz));
      }
      #pragma unroll
      for (int ni = 0; ni < 4; ++ni){
        const int row = wc*64 + ni*16 + lr;
        bf[ni] = *(const s16x8*)(Bt + row*128 + ((s*64 + g*16) ^ swz));
      }
      __builtin_amdgcn_s_setprio(1);
      #pragma unroll
      for (int mi = 0; mi < 4; ++mi)
        #pragma unroll
        for (int ni = 0; ni < 4; ++ni)
          acc[mi][ni] = __builtin_amdgcn_mfma_f32_16x16x32_bf16(af[mi], bf[ni], acc[mi][ni], 0, 0, 0);
      __builtin_amdgcn_s_setprio(0);
    }

    asm volatile("s_barrier" ::: "memory");  // all waves done reading buf[cur]
    if (t + 2 < nk) stage(t + 2, cur);       // refill buf[cur] for tile t+2
  }

  #pragma unroll
  for (int mi = 0; mi < 4; ++mi){
    #pragma unroll
    for (int ni = 0; ni < 4; ++ni){
      const int n = n0 + wc*64 + ni*16 + lr;
      const float bv = bias[n];
      #pragma unroll
      for (int r = 0; r < 4; ++r){
        const int m = m0 + wr*64 + mi*16 + g*4 + r;
        const float val = acc[mi][ni][r] + bv;
        if (MODE == 0){
          const int which = n >> 10;
          const int cc = n & 1023;
          const int h = cc >> 6, d = cc & 63;
          const int bq = m >> 11, t = m & 2047;
          const int bh = bq*16 + h;
          // q pre-scaled by log2(e)/64 so attention works in exp2 domain
          if (which == 0)      q_ws[((size_t)bh*T_ + t)*D_ + d] = f2bf(val * 0.022542110013890054f);
          else if (which == 1) k_ws[((size_t)bh*T_ + t)*D_ + d] = f2bf(val);
          else                 vT_ws[((size_t)bh*D_ + d)*T_ + t] = f2bf(val);
        } else {
          out[(size_t)m*N + n] = val;
        }
      }
    }
  }
}

// ---------------- flash attention v5: balanced pairs, shared K/V staging ----------------
__global__ __launch_bounds__(256, 4) void attn_kernel(
    const unsigned short* __restrict__ q_ws, const unsigned short* __restrict__ k_ws,
    const unsigned short* __restrict__ vT_ws, unsigned short* __restrict__ y_ws)
{
  __shared__ __align__(16) unsigned short Ks[2][64*64];   // [key][d]  8KB x2 (P aliases Ks[cur])
  __shared__ __align__(16) unsigned short Vs[2][64*64];   // [d][key]  8KB x2

  const int tid = threadIdx.x;
  const int lane = tid & 63, wid = tid >> 6;
  const int g = lane >> 4, lr = lane & 15;
  const int orig = (int)blockIdx.x;
  const int wgid = (orig & 7) * 128 + (orig >> 3);        // XCD-chunk
  const int p  = wgid & 15;
  const int bh = wgid >> 4;
  const int qwA = p*64 + wid*16,  qwB = (31 - p)*64 + wid*16;
  const int qrowA = qwA + lr,     qrowB = qwB + lr;
  const int swz = (lr & 7) << 4;

  const unsigned short* Qb = q_ws  + (size_t)bh*T_*D_;
  const unsigned short* Kb = k_ws  + (size_t)bh*T_*D_;
  const unsigned short* Vb = vT_ws + (size_t)bh*D_*T_;

  auto stage = [&](int t, int buf){
    const int kt0 = t << 6;
    #pragma unroll
    for (int s = 0; s < 2; ++s){
      const int c = s*256 + tid;
      const int r = c >> 3;
      const int scol = ((c & 7) << 4) ^ ((r & 7) << 4);
      gload_lds16((const char*)Kb + ((size_t)(kt0 + r)*D_)*2 + scol,
                  (char*)&Ks[buf][0] + c*16);
      gload_lds16((const char*)Vb + ((size_t)r*T_ + kt0)*2 + scol,
                  (char*)&Vs[buf][0] + c*16);
    }
  };

  const s16x8 bqA0 = *(const s16x8*)&Qb[(size_t)(qwA+lr)*D_ + g*8];
  const s16x8 bqA1 = *(const s16x8*)&Qb[(size_t)(qwA+lr)*D_ + 32 + g*8];
  const s16x8 bqB0 = *(const s16x8*)&Qb[(size_t)(qwB+lr)*D_ + g*8];
  const s16x8 bqB1 = *(const s16x8*)&Qb[(size_t)(qwB+lr)*D_ + 32 + g*8];

  s16x8 ones;
  #pragma unroll
  for (int j = 0; j < 8; ++j) ones[j] = (short)0x3F80;

  f32x4 yA[4], yB[4];
  #pragma unroll
  for (int dt = 0; dt < 4; ++dt){ yA[dt] = (f32x4){0.f,0.f,0.f,0.f}; yB[dt] = (f32x4){0.f,0.f,0.f,0.f}; }
  f32x4 lacA = (f32x4){0.f,0.f,0.f,0.f}, lacB = (f32x4){0.f,0.f,0.f,0.f};
  float mA = -1e30f, mB = -1e30f;

  const int ntA = p + 1, ntB = 32 - p;
  stage(0, 0);
  __syncthreads();

  for (int t = 0; t < ntB; ++t){
    const int cur = t & 1;
    if (t + 1 < ntB) stage(t + 1, cur ^ 1);
    const int kt0 = t << 6;
    const unsigned short* Kt = &Ks[cur][0];
    const unsigned short* Vt = &Vs[cur][0];
    unsigned short* Pw = &Ks[cur][wid*1024];
    const bool actA = (t < ntA);                 // wave-uniform

    f32x4 sB[4], sA[4];
    #pragma unroll
    for (int kk = 0; kk < 4; ++kk){
      const int row = kk*16 + lr;
      const s16x8 a0 = *(const s16x8*)&Kt[row*64 + (((g*16)      ^ swz) >> 1)];
      const s16x8 a1 = *(const s16x8*)&Kt[row*64 + (((64 + g*16) ^ swz) >> 1)];
      f32x4 acc = (f32x4){0.f,0.f,0.f,0.f};
      acc = __builtin_amdgcn_mfma_f32_16x16x32_bf16(a0, bqB0, acc, 0, 0, 0);
      acc = __builtin_amdgcn_mfma_f32_16x16x32_bf16(a1, bqB1, acc, 0, 0, 0);
      sB[kk] = acc;
      if (actA){
        f32x4 acc2 = (f32x4){0.f,0.f,0.f,0.f};
        acc2 = __builtin_amdgcn_mfma_f32_16x16x32_bf16(a0, bqA0, acc2, 0, 0, 0);
        acc2 = __builtin_amdgcn_mfma_f32_16x16x32_bf16(a1, bqA1, acc2, 0, 0, 0);
        sA[kk] = acc2;
      }
    }

    if (kt0 + 63 > qwB){
      #pragma unroll
      for (int kk = 0; kk < 4; ++kk)
        #pragma unroll
        for (int r = 0; r < 4; ++r)
          if (kt0 + kk*16 + g*4 + r > qrowB) sB[kk][r] = -1e30f;
    }
    {
      float m01 = fmaxf(fmaxf(sB[0][0], sB[0][1]), fmaxf(sB[0][2], sB[0][3]));
      float m23 = fmaxf(fmaxf(sB[1][0], sB[1][1]), fmaxf(sB[1][2], sB[1][3]));
      float m45 = fmaxf(fmaxf(sB[2][0], sB[2][1]), fmaxf(sB[2][2], sB[2][3]));
      float m67 = fmaxf(fmaxf(sB[3][0], sB[3][1]), fmaxf(sB[3][2], sB[3][3]));
      float mx = fmaxf(fmaxf(m01, m23), fmaxf(m45, m67));
      mx = fmaxf(mx, __shfl_xor(mx, 16, 64));
      mx = fmaxf(mx, __shfl_xor(mx, 32, 64));
      if (!__all(mx <= mB + 8.f)){
        const float mnew = fmaxf(mB, mx);
        const float corr = exp2_asm(mB - mnew);
        mB = mnew;
        lacB[0] *= corr;
        #pragma unroll
        for (int dt = 0; dt < 4; ++dt)
          #pragma unroll
          for (int r = 0; r < 4; ++r) yB[dt][r] *= corr;
      }
    }
    union { unsigned int u[2]; u16x4 v; } pkB[4];
    #pragma unroll
    for (int kk = 0; kk < 4; ++kk){
      const float e0 = exp2_asm(sB[kk][0] - mB);
      const float e1 = exp2_asm(sB[kk][1] - mB);
      const float e2 = exp2_asm(sB[kk][2] - mB);
      const float e3 = exp2_asm(sB[kk][3] - mB);
      pkB[kk].u[0] = cvtpk(e0, e1);
      pkB[kk].u[1] = cvtpk(e2, e3);
    }

    asm volatile("s_barrier" ::: "memory");

    #pragma unroll
    for (int kk = 0; kk < 4; ++kk)
      *(u16x4*)&Pw[lr*64 + (((kk*32 + g*8) ^ swz) >> 1)] = pkB[kk].v;
    asm volatile("" ::: "memory");
    {
      const s16x8 p0 = *(const s16x8*)&Pw[lr*64 + (((g*16)      ^ swz) >> 1)];
      const s16x8 p1 = *(const s16x8*)&Pw[lr*64 + (((64 + g*16) ^ swz) >> 1)];
      lacB = __builtin_amdgcn_mfma_f32_16x16x32_bf16(ones, p0, lacB, 0, 0, 0);
      lacB = __builtin_amdgcn_mfma_f32_16x16x32_bf16(ones, p1, lacB, 0, 0, 0);
      #pragma unroll
      for (int dt = 0; dt < 4; ++dt){
        const int vrow = dt*16 + lr;
        const s16x8 v0 = *(const s16x8*)&Vt[vrow*64 + (((g*16)      ^ swz) >> 1)];
        const s16x8 v1 = *(const s16x8*)&Vt[vrow*64 + (((64 + g*16) ^ swz) >> 1)];
        yB[dt] = __builtin_amdgcn_mfma_f32_16x16x32_bf16(v0, p0, yB[dt], 0, 0, 0);
        yB[dt] = __builtin_amdgcn_mfma_f32_16x16x32_bf16(v1, p1, yB[dt], 0, 0, 0);
      }
    }

    if (actA){
      if (kt0 + 63 > qwA){
        #pragma unroll
        for (int kk = 0; kk < 4; ++kk)
          #pragma unroll
          for (int r = 0; r < 4; ++r)
            if (kt0 + kk*16 + g*4 + r > qrowA) sA[kk][r] = -1e30f;
      }
      float m01 = fmaxf(fmaxf(sA[0][0], sA[0][1]), fmaxf(sA[0][2], sA[0][3]));
      float m23 = fmaxf(fmaxf(sA[1][0], sA[1][1]), fmaxf(sA[1][2], sA[1][3]));
      float m45 = fmaxf(fmaxf(sA[2][0], sA[2][1]), fmaxf(sA[2][2], sA[2][3]));
      float m67 = fmaxf(fmaxf(sA[3][0], sA[3][1]), fmaxf(sA[3][2], sA[3][3]));
      float mx = fmaxf(fmaxf(m01, m23), fmaxf(m45, m67));
      mx = fmaxf(mx, __shfl_xor(mx, 16, 64));
      mx = fmaxf(mx, __shfl_xor(mx, 32, 64));
      if (!__all(mx <= mA + 8.f)){
        const float mnew = fmaxf(mA, mx);
        const float corr = exp2_asm(mA - mnew);
        mA = mnew;
        lacA[0] *= corr;
        #pragma unroll
        for (int dt = 0; dt < 4; ++dt)
          #pragma unroll
          for (int r = 0; r < 4; ++r) yA[dt][r] *= corr;
      }
      union { unsigned int u[2]; u16x4 v; } pkA[4];
      #pragma unroll
      for (int kk = 0; kk < 4; ++kk){
        const float e0 = exp2_asm(sA[kk][0] - mA);
        const float e1 = exp2_asm(sA[kk][1] - mA);
        const float e2 = exp2_asm(sA[kk][2] - mA);
        const float e3 = exp2_asm(sA[kk][3] - mA);
        pkA[kk].u[0] = cvtpk(e0, e1);
        pkA[kk].u[1] = cvtpk(e2, e3);
      }
      asm volatile("" ::: "memory");
      #pragma unroll
      for (int kk = 0; kk < 4; ++kk)
        *(u16x4*)&Pw[lr*64 + (((kk*32 + g*8) ^ swz) >> 1)] = pkA[kk].v;
      asm volatile("" ::: "memory");
      const s16x8 p0 = *(const s16x8*)&Pw[lr*64 + (((g*16)      ^ swz) >> 1)];
      const s16x8 p1 = *(const s16x8*)&Pw[lr*64 + (((64 + g*16) ^ swz) >> 1)];
      lacA = __builtin_amdgcn_mfma_f32_16x16x32_bf16(ones, p0, lacA, 0, 0, 0);
      lacA = __builtin_amdgcn_mfma_f32_16x16x32_bf16(ones, p1, lacA, 0, 0, 0);
      #pragma unroll
      for (int dt = 0; dt < 4; ++dt){
        const int vrow = dt*16 + lr;
        const s16x8 v0 = *(const s16x8*)&Vt[vrow*64 + (((g*16)      ^ swz) >> 1)];
        const s16x8 v1 = *(const s16x8*)&Vt[vrow*64 + (((64 + g*16) ^ swz) >> 1)];
        yA[dt] = __builtin_amdgcn_mfma_f32_16x16x32_bf16(v0, p0, yA[dt], 0, 0, 0);
        yA[dt] = __builtin_amdgcn_mfma_f32_16x16x32_bf16(v1, p1, yA[dt], 0, 0, 0);
      }
    }

    __syncthreads();
  }

  const int bq = bh >> 4, h = bh & 15;
  {
    const float inv = 1.f / lacB[0];
    #pragma unroll
    for (int dt = 0; dt < 4; ++dt){
      union { unsigned int u[2]; u16x4 v; } w;
      w.u[0] = cvtpk(yB[dt][0]*inv, yB[dt][1]*inv);
      w.u[1] = cvtpk(yB[dt][2]*inv, yB[dt][3]*inv);
      *(u16x4*)&y_ws[((size_t)(bq*T_ + qwB + lr))*C_ + h*64 + dt*16 + g*4] = w.v;
    }
  }
  {
    const float inv = 1.f / lacA[0];
    #pragma unroll
    for (int dt = 0; dt < 4; ++dt){
      union { unsigned int u[2]; u16x4 v; } w;
      w.u[0] = cvtpk(yA[dt][0]*inv, yA[dt][1]*inv);
      w.u[1] = cvtpk(yA[dt][2]*inv, yA[dt][3]*inv);
      *(u16x4*)&y_ws[((size_t)(bq*T_ + qwA + lr))*C_ + h*64 + dt*16 + g*4] = w.v;
    }
  }
}

extern "C" void kernel_launch(void* const* d_in, const int* in_sizes, int n_in,
                              void* d_out, int out_size, void* d_ws, size_t ws_size,
                              hipStream_t stream) {
  const float* x  = (const float*)d_in[0];
  const float* Wa = (const float*)d_in[1];
  const float* ba = (const float*)d_in[2];
  const float* Wp = (const float*)d_in[3];
  const float* bp = (const float*)d_in[4];
  float* out = (float*)d_out;

  char* ws = (char*)d_ws;
  const size_t MB = 1024u*1024u;
  unsigned short* xb  = (unsigned short*)(ws + 0);       // 16 MiB  [8192][1024] bf16
  unsigned short* wab = (unsigned short*)(ws + 16*MB);   //  6 MiB  [3072][1024]
  unsigned short* wpb = (unsigned short*)(ws + 22*MB);   //  2 MiB  [1024][1024]
  unsigned short* qws = (unsigned short*)(ws + 24*MB);   // 16 MiB  [64][2048][64]
  unsigned short* kws = (unsigned short*)(ws + 40*MB);   // 16 MiB  [64][2048][64]
  unsigned short* vT  = (unsigned short*)(ws + 56*MB);   // 16 MiB  [64][64][2048]
  unsigned short* yws = (unsigned short*)(ws + 72*MB);   // 16 MiB  [8192][1024]

  cvt_kernel<<<4096, 256, 0, stream>>>(x,  xb);
  cvt_kernel<<<1536, 256, 0, stream>>>(Wa, wab);
  cvt_kernel<<< 512, 256, 0, stream>>>(Wp, wpb);

  // QKV: M=8192 (64 tiles), N=3072 (24 tiles) -> 1536 blocks, 2 resident/CU
  gemm_bt<0><<<dim3(1536), 256, 0, stream>>>(xb, wab, ba, 8192, 3072, 1024, 24,
                                             qws, kws, vT, nullptr);
  attn_kernel<<<dim3(1024), 256, 0, stream>>>(qws, kws, vT, yws);
  // proj: M=8192, N=1024 (8 tiles) -> 512 blocks
  gemm_bt<1><<<dim3(512), 256, 0, stream>>>(yws, wpb, bp, 8192, 1024, 1024, 8,
                                            nullptr, nullptr, nullptr, out);
}